// Round 1
// baseline (6861.549 us; speedup 1.0000x reference)
//
#include <hip/hip_runtime.h>
#include <hip/hip_bf16.h>

// ---------------------------------------------------------------------------
// LSTM_66675072303478: 2-layer LSTM (B=512,S=128,E=7,H=1024) + FC(1024->672)
//
// Strategy v1:
//  - Weights pre-converted to bf16, gate-interleaved layout so that the four
//    gates (i,f,g,o) for a given hidden column land in the same lane's four
//    16x16 MFMA fragments -> LSTM cell update fused into GEMM epilogue.
//  - Per step t: GEMM0 (K=1024, h_a @ Wh0^T, + fp32 epilogue x_t@Wi0^T + b0),
//                GEMM1 (K=2048, [h_a(t), h_b(t-1)] @ [Wi1|Wh1]^T + b1).
//  - h stored bf16 in ping-pong A buffers (512x2048: [h_a | h_b]); c fp32.
//  - Final FC via the same GEMM skeleton (plain layout, N padded to 768).
// ---------------------------------------------------------------------------

typedef __bf16 bf16x8 __attribute__((ext_vector_type(8)));
typedef float  f32x4  __attribute__((ext_vector_type(4)));

#define LDST 40   // LDS row stride in bf16 elems (32 + 8 pad -> <=2-way conflicts)

__device__ __forceinline__ float sigm_f(float x) {
    x = fminf(30.f, fmaxf(-30.f, x));
    return 1.0f / (1.0f + __expf(-x));
}
__device__ __forceinline__ float tanh_f(float x) {
    x = fminf(30.f, fmaxf(-30.f, x));
    float e = __expf(-2.0f * x);
    return (1.0f - e) / (1.0f + e);
}

// n' = (j/16)*64 + g*16 + (j%16)  ->  original gate-major row g*1024 + j
__device__ __forceinline__ int perm_row(int np) {
    int g = (np >> 4) & 3;
    int j = ((np >> 6) << 4) | (np & 15);
    return g * 1024 + j;
}

// ---------------- weight prep kernels (run every call; ws is re-poisoned) ---

__global__ void prep_w0(const float* __restrict__ Wh0, __bf16* __restrict__ W0p) {
    int idx = blockIdx.x * 256 + threadIdx.x;      // 4096 rows x 256 thr (x4 elems)
    int np = idx >> 8, k4 = (idx & 255) << 2;
    int r = perm_row(np);
    float4 v = *(const float4*)(Wh0 + r * 1024 + k4);
    __bf16* o = W0p + np * 1024 + k4;
    o[0] = (__bf16)v.x; o[1] = (__bf16)v.y; o[2] = (__bf16)v.z; o[3] = (__bf16)v.w;
}

__global__ void prep_w1(const float* __restrict__ Wi1, const float* __restrict__ Wh1,
                        __bf16* __restrict__ W1p) {
    int idx = blockIdx.x * 256 + threadIdx.x;      // 4096 rows x 512 thr (x4 elems)
    int np = idx >> 9, k4 = (idx & 511) << 2;
    int r = perm_row(np);
    const float* s = (k4 < 1024) ? (Wi1 + r * 1024 + k4) : (Wh1 + r * 1024 + (k4 - 1024));
    float4 v = *(const float4*)s;
    __bf16* o = W1p + np * 2048 + k4;
    o[0] = (__bf16)v.x; o[1] = (__bf16)v.y; o[2] = (__bf16)v.z; o[3] = (__bf16)v.w;
}

__global__ void prep_wfc(const float* __restrict__ Wfc, __bf16* __restrict__ Wfcp) {
    int idx = blockIdx.x * 256 + threadIdx.x;      // 768 rows x 256 thr (x4 elems)
    int n = idx >> 8, k4 = (idx & 255) << 2;
    __bf16* o = Wfcp + n * 1024 + k4;
    if (n < 672) {
        float4 v = *(const float4*)(Wfc + n * 1024 + k4);
        o[0] = (__bf16)v.x; o[1] = (__bf16)v.y; o[2] = (__bf16)v.z; o[3] = (__bf16)v.w;
    } else {
        o[0] = (__bf16)0.f; o[1] = (__bf16)0.f; o[2] = (__bf16)0.f; o[3] = (__bf16)0.f;
    }
}

__global__ void prep_small(const float* __restrict__ Wi0, const float* __restrict__ b0,
                           const float* __restrict__ b1,
                           float* __restrict__ Wi0p, float* __restrict__ b1p) {
    int np = blockIdx.x * 256 + threadIdx.x;       // 4096 threads
    int r = perm_row(np);
    float* o = Wi0p + np * 8;
    #pragma unroll
    for (int q = 0; q < 7; ++q) o[q] = Wi0[r * 7 + q];
    o[7] = b0[r];
    b1p[np] = b1[r];
}

// ---------------- fused GEMM + LSTM-cell / FC kernel ------------------------
// Tile: BM=64 x BN=128, BK=32, 256 threads = 4 waves in 2x2, wave tile 32x64.
// EPI: 0 = LSTM layer0 (x-dot + b0 in epilogue), 1 = LSTM layer1 (+b1),
//      2 = FC (write fp32 out + bfc, guard n<672).

template <int KTOT, int EPI>
__global__ __launch_bounds__(256)
void gemm_step(const __bf16* __restrict__ Alo,   // rows m, lda=2048, k in [0,1024)
               const __bf16* __restrict__ Ahi,   // k in [1024,2048) -> Ahi + (k-1024)
               const __bf16* __restrict__ W,     // (N x KTOT) bf16, row-major
               const float* __restrict__ aux,    // EPI0: Wi0p(4096x8); EPI1: b1p; EPI2: bfc
               const float* __restrict__ xt,     // EPI0: x + t*7 (row stride 896)
               float* __restrict__ Cst,          // EPI0/1: c-state (512x1024); EPI2: out
               __bf16* __restrict__ Hout)        // EPI0/1: h out, row stride 2048
{
    __shared__ __attribute__((aligned(16))) __bf16 Alds[64 * LDST];
    __shared__ __attribute__((aligned(16))) __bf16 Blds[128 * LDST];
    __shared__ float Aux1[128];
    __shared__ float Xlds[64 * 9];
    __shared__ float Wxlds[128 * 9];

    const int tid = threadIdx.x;
    const int n0 = blockIdx.x * 128;
    const int m0 = blockIdx.y * 64;

    // stage epilogue inputs
    if (EPI == 0) {
        if (tid < 64) {
            const float* xr = xt + (m0 + tid) * 896;
            float* d = Xlds + tid * 9;
            #pragma unroll
            for (int q = 0; q < 7; ++q) d[q] = xr[q];
            d[7] = 1.0f;
        } else if (tid < 192) {
            int nl = tid - 64;
            const float* s = aux + (n0 + nl) * 8;
            float* d = Wxlds + nl * 9;
            #pragma unroll
            for (int q = 0; q < 8; ++q) d[q] = s[q];
        }
    } else {
        if (tid < 128) {
            int n = n0 + tid;
            Aux1[tid] = (EPI == 1) ? aux[n] : ((n < 672) ? aux[n] : 0.0f);
        }
    }

    // staging map: thread t -> row t/4, 8-elem chunk (t%4)*8
    const int a_r = tid >> 2;
    const int a_c = (tid & 3) << 3;

    uint4 ra, rb0, rb1;
    {   // prefetch k-chunk 0
        ra  = *(const uint4*)(Alo + (m0 + a_r) * 2048 + a_c);
        rb0 = *(const uint4*)(W + (n0 + a_r) * KTOT + a_c);
        rb1 = *(const uint4*)(W + (n0 + a_r + 64) * KTOT + a_c);
    }

    const int l  = tid & 63, w = tid >> 6;
    const int wm = w & 1,   wn = w >> 1;
    const int lj = l & 15,  lq = l >> 4;

    f32x4 acc[2][4];
    #pragma unroll
    for (int i = 0; i < 2; ++i)
        #pragma unroll
        for (int j = 0; j < 4; ++j)
            acc[i][j] = (f32x4){0.f, 0.f, 0.f, 0.f};

    const int NIT = KTOT / 32;
    for (int it = 0; it < NIT; ++it) {
        __syncthreads();
        *(uint4*)(Alds + a_r * LDST + a_c) = ra;
        *(uint4*)(Blds + a_r * LDST + a_c) = rb0;
        *(uint4*)(Blds + (a_r + 64) * LDST + a_c) = rb1;
        __syncthreads();
        if (it + 1 < NIT) {
            int k0 = (it + 1) * 32;
            const __bf16* Ab = (k0 < 1024) ? (Alo + k0) : (Ahi + (k0 - 1024));
            ra  = *(const uint4*)(Ab + (m0 + a_r) * 2048 + a_c);
            rb0 = *(const uint4*)(W + (n0 + a_r) * KTOT + k0 + a_c);
            rb1 = *(const uint4*)(W + (n0 + a_r + 64) * KTOT + k0 + a_c);
        }
        const __bf16* Ap = Alds + (wm * 32 + lj) * LDST + lq * 8;
        bf16x8 af0 = *(const bf16x8*)(Ap);
        bf16x8 af1 = *(const bf16x8*)(Ap + 16 * LDST);
        const __bf16* Bp = Blds + (wn * 64 + lj) * LDST + lq * 8;
        #pragma unroll
        for (int ni = 0; ni < 4; ++ni) {
            bf16x8 bfr = *(const bf16x8*)(Bp + ni * 16 * LDST);
            acc[0][ni] = __builtin_amdgcn_mfma_f32_16x16x32_bf16(af0, bfr, acc[0][ni], 0, 0, 0);
            acc[1][ni] = __builtin_amdgcn_mfma_f32_16x16x32_bf16(af1, bfr, acc[1][ni], 0, 0, 0);
        }
    }

    // epilogue
    if (EPI == 2) {
        #pragma unroll
        for (int mi = 0; mi < 2; ++mi) {
            #pragma unroll
            for (int r = 0; r < 4; ++r) {
                int m = m0 + wm * 32 + mi * 16 + lq * 4 + r;
                #pragma unroll
                for (int ni = 0; ni < 4; ++ni) {
                    int n = n0 + wn * 64 + ni * 16 + lj;
                    if (n < 672)
                        Cst[m * 672 + n] = acc[mi][ni][r] + Aux1[wn * 64 + ni * 16 + lj];
                }
            }
        }
    } else {
        #pragma unroll
        for (int mi = 0; mi < 2; ++mi) {
            #pragma unroll
            for (int r = 0; r < 4; ++r) {
                int ml = wm * 32 + mi * 16 + lq * 4 + r;
                int m  = m0 + ml;
                float pre[4];
                #pragma unroll
                for (int g = 0; g < 4; ++g) pre[g] = acc[mi][g][r];
                if (EPI == 0) {
                    const float* xr = Xlds + ml * 9;
                    #pragma unroll
                    for (int g = 0; g < 4; ++g) {
                        const float* wx = Wxlds + (wn * 64 + g * 16 + lj) * 9;
                        float s = 0.f;
                        #pragma unroll
                        for (int q = 0; q < 8; ++q) s += xr[q] * wx[q];
                        pre[g] += s;
                    }
                } else {
                    #pragma unroll
                    for (int g = 0; g < 4; ++g) pre[g] += Aux1[wn * 64 + g * 16 + lj];
                }
                int j = (n0 >> 2) + wn * 16 + lj;       // global hidden column
                float* cp = Cst + m * 1024 + j;
                float cold = *cp;
                float ig = sigm_f(pre[0]);
                float fg = sigm_f(pre[1]);
                float gg = tanh_f(pre[2]);
                float og = sigm_f(pre[3]);
                float cn = fg * cold + ig * gg;
                *cp = cn;
                Hout[m * 2048 + j] = (__bf16)(og * tanh_f(cn));
            }
        }
    }
}

// ---------------- workspace layout (bytes) ----------------------------------
#define O_W0P   0u            // 4096*1024*2  = 8388608
#define O_W1P   8388608u      // 4096*2048*2  = 16777216
#define O_WFCP  25165824u     // 768*1024*2   = 1572864
#define O_WI0P  26738688u     // 4096*8*4     = 131072
#define O_B1P   26869760u     // 4096*4       = 16384
#define O_AB0   26886144u     // 512*2048*2   = 2097152
#define O_CA    28983296u     // 512*1024*4   = 2097152
#define O_CB    31080448u     // 512*1024*4   = 2097152
#define O_AB1   33177600u     // 512*2048*2   = 2097152
#define WS_NEED 35274752u

extern "C" void kernel_launch(void* const* d_in, const int* in_sizes, int n_in,
                              void* d_out, int out_size, void* d_ws, size_t ws_size,
                              hipStream_t stream) {
    const float* x   = (const float*)d_in[0];
    const float* Wi0 = (const float*)d_in[1];
    const float* Wh0 = (const float*)d_in[2];
    const float* b0  = (const float*)d_in[3];
    const float* Wi1 = (const float*)d_in[4];
    const float* Wh1 = (const float*)d_in[5];
    const float* b1  = (const float*)d_in[6];
    const float* Wfc = (const float*)d_in[7];
    const float* bfc = (const float*)d_in[8];
    float* out = (float*)d_out;
    char*  ws  = (char*)d_ws;
    if (ws_size < WS_NEED) return;   // would need bigger scratch

    __bf16* W0p  = (__bf16*)(ws + O_W0P);
    __bf16* W1p  = (__bf16*)(ws + O_W1P);
    __bf16* Wfcp = (__bf16*)(ws + O_WFCP);
    float*  Wi0p = (float*)(ws + O_WI0P);
    float*  b1p  = (float*)(ws + O_B1P);
    __bf16* Ab0  = (__bf16*)(ws + O_AB0);
    float*  ca   = (float*)(ws + O_CA);
    float*  cb   = (float*)(ws + O_CB);
    __bf16* Ab1  = (__bf16*)(ws + O_AB1);

    // zero h ping buffer 0 + both c states (contiguous 6 MB region)
    hipMemsetAsync(ws + O_AB0, 0, 3u * 2097152u, stream);

    prep_w0   <<<4096, 256, 0, stream>>>(Wh0, W0p);
    prep_w1   <<<8192, 256, 0, stream>>>(Wi1, Wh1, W1p);
    prep_wfc  <<<768,  256, 0, stream>>>(Wfc, Wfcp);
    prep_small<<<16,   256, 0, stream>>>(Wi0, b0, b1, Wi0p, b1p);

    dim3 blk(256), gl(32, 8);
    for (int t = 0; t < 128; ++t) {
        __bf16* Acur = (t & 1) ? Ab1 : Ab0;
        __bf16* Anxt = (t & 1) ? Ab0 : Ab1;
        // layer 0: gates = h_a(t-1) @ Wh0p^T (+ x_t@Wi0^T + b0 in epilogue)
        gemm_step<1024, 0><<<gl, blk, 0, stream>>>(Acur, Acur, W0p, Wi0p,
                                                   x + t * 7, ca, Anxt);
        // layer 1: gates = [h_a(t) | h_b(t-1)] @ [Wi1|Wh1]p^T + b1
        gemm_step<2048, 1><<<gl, blk, 0, stream>>>(Anxt, Acur + 1024, W1p, b1p,
                                                   nullptr, cb, Anxt + 1024);
    }
    // final h_b lives in Ab0[:,1024:2048) (t=127 wrote into buffer 0)
    dim3 gf(6, 8);
    gemm_step<1024, 2><<<gf, blk, 0, stream>>>(Ab0 + 1024, Ab0 + 1024, Wfcp, bfc,
                                               nullptr, out, nullptr);
}